// Round 9
// baseline (470.080 us; speedup 1.0000x reference)
//
#include <hip/hip_runtime.h>
#include <math.h>

// Problem constants (from reference)
#define N_SAMP 200000
#define D_     128
#define T_     8
#define P_     2000
#define NP_    9
#define H_     2048
#define MPAD   2048          // padded M for guard-free MFMA GEMM
#define NSEG   16000

// ---------------------------------------------------------------------------
// Workspace layout (bytes). Zero region [0, ZERO_BYTES) covered by ONE memset:
//   pt_sum | cnt(f32) | tsum | tcnt | fmax.  h2 overlays {fphi..w1tlo}
// (dead after GEMM1; exactly 16,777,216 B). Total ~58.6 MB.
// ---------------------------------------------------------------------------
#define OFF_PTSUM   0                  // 16000*128 f32 = 8,192,000
#define OFF_CNT     8192000            // 16000 f32    = 64,000
#define OFF_TSUM    8256000            // 1024 f32     = 4,096
#define OFF_TCNT    8260096            // 8 f32 (pad 256)
#define OFF_FMAX    8260352            // 2000 u32     = 8,000
#define ZERO_BYTES  8268352
#define OFF_FPHI    8268544            // 2048*1024 bf16 = 4,194,304
#define OFF_FPLO    12462848
#define OFF_W1THI   16657152
#define OFF_W1TLO   20851456
#define OFF_H1HI    25045760           // 2048*2048 bf16 = 8,388,608
#define OFF_H1LO    33434368
#define OFF_W2THI   41822976
#define OFF_W2TLO   50211584
#define OFF_H2      OFF_FPHI           // overlay (16,777,216 B exactly)

typedef __attribute__((ext_vector_type(8))) short bf16x8;
typedef __attribute__((ext_vector_type(4))) float f32x4;

// bf16 split helpers (bit ops, RNE)
__device__ __forceinline__ unsigned f2bf_rne(float x) {
    unsigned b = __float_as_uint(x);
    return (b + 0x7fffu + ((b >> 16) & 1u)) >> 16;
}
__device__ __forceinline__ float bf2f(unsigned u) {
    return __uint_as_float(u << 16);
}

// async global->LDS, 16B/lane: LDS dest = wave-uniform base + lane*16 [m97/m104]
__device__ __forceinline__ void gload16(const void* g, void* l) {
    __builtin_amdgcn_global_load_lds(
        (const __attribute__((address_space(1))) unsigned int*)g,
        (__attribute__((address_space(3))) unsigned int*)l, 16, 0, 0);
}

// ---------------------------------------------------------------------------
// Kernel 1: block-compaction scatter (R8-measured). Threads scan masks
// coalescedly, push valid (seg,row) into an LDS list; waves drain the list.
// ---------------------------------------------------------------------------
__global__ __launch_bounds__(256) void scatter_pt(
    const float* __restrict__ motion_z, const int* __restrict__ tasks,
    const int* __restrict__ tmask, const int* __restrict__ pids,
    const int* __restrict__ pmask, float* __restrict__ pt_sum,
    float* __restrict__ cnt, unsigned* __restrict__ fmax)
{
    __shared__ unsigned list[256];
    __shared__ int nvalid;
    int tid  = threadIdx.x;
    int lane = tid & 63;
    int wv   = tid >> 6;
    for (int base = blockIdx.x * 256; base < N_SAMP; base += gridDim.x * 256) {
        if (tid == 0) nvalid = 0;
        __syncthreads();
        int i = base + tid;
        if (i < N_SAMP && tmask[i] == 1 && pmask[i] == 1) {
            int p = pids[i];
            int seg = p * T_ + tasks[i];
            atomicAdd(&cnt[seg], 1.0f);
            atomicMax(&fmax[p], (unsigned)(N_SAMP - i));
            int pos = atomicAdd(&nvalid, 1);
            list[pos] = ((unsigned)seg << 18) | (unsigned)i;   // seg<16384, i<2^18
        }
        __syncthreads();
        int nv = nvalid;
        for (int e = wv; e < nv; e += 4) {
            unsigned pk = list[e];
            int row = (int)(pk & 0x3FFFFu);
            int seg = (int)(pk >> 18);
            float2 v = *(const float2*)&motion_z[(size_t)row * D_ + lane * 2];
            atomicAdd(&pt_sum[seg * D_ + lane * 2 + 0], v.x);
            atomicAdd(&pt_sum[seg * D_ + lane * 2 + 1], v.y);
        }
        __syncthreads();
    }
}

// ---------------------------------------------------------------------------
// Kernel 2 (fused): blocks [0,125) task-sum partials; rest weight transpose.
// ---------------------------------------------------------------------------
__global__ __launch_bounds__(256) void mid_fused(
    const float* __restrict__ pt_sum, const float* __restrict__ cnt,
    float* __restrict__ tsum, float* __restrict__ tcnt,
    const float* __restrict__ W1, const float* __restrict__ W2,
    unsigned short* __restrict__ w1hi, unsigned short* __restrict__ w1lo,
    unsigned short* __restrict__ w2hi, unsigned short* __restrict__ w2lo)
{
    __shared__ float tile[32][33];
    int tid = threadIdx.x;
    if (blockIdx.x < 125) {
        int p0 = blockIdx.x * 16;
        float4 acc = make_float4(0.f, 0.f, 0.f, 0.f);
        for (int pl = 0; pl < 16; ++pl) {
            float4 v = *(const float4*)&pt_sum[(size_t)(p0 + pl) * 1024 + tid * 4];
            acc.x += v.x; acc.y += v.y; acc.z += v.z; acc.w += v.w;
        }
        atomicAdd(&tsum[tid * 4 + 0], acc.x);
        atomicAdd(&tsum[tid * 4 + 1], acc.y);
        atomicAdd(&tsum[tid * 4 + 2], acc.z);
        atomicAdd(&tsum[tid * 4 + 3], acc.w);
        if (tid < 128) {
            int p = p0 + (tid >> 3), t = tid & 7;
            atomicAdd(&tcnt[t], cnt[p * 8 + t]);
        }
        return;
    }
    int id = blockIdx.x - 125;
    const float* W; unsigned short *Whi, *Wlo; int K;
    if (id < 2048) { W = W1; Whi = w1hi; Wlo = w1lo; K = 1024; }
    else { id -= 2048; W = W2; Whi = w2hi; Wlo = w2lo; K = 2048; }
    int bx = id & 63, by = id >> 6;
    int k0 = by * 32, n0 = bx * 32;
    const int N = 2048;
    int r = tid >> 3, c4 = (tid & 7) * 4;
    float4 v = *(const float4*)&W[(size_t)(k0 + r) * N + n0 + c4];
    tile[r][c4 + 0] = v.x; tile[r][c4 + 1] = v.y;
    tile[r][c4 + 2] = v.z; tile[r][c4 + 3] = v.w;
    __syncthreads();
    unsigned short hi[4], lo[4];
#pragma unroll
    for (int q = 0; q < 4; ++q) {
        float x = tile[c4 + q][r];
        unsigned h = f2bf_rne(x);
        hi[q] = (unsigned short)h;
        lo[q] = (unsigned short)f2bf_rne(x - bf2f(h));
    }
    size_t o = (size_t)(n0 + r) * K + k0 + c4;
    *(ushort4*)&Whi[o] = make_ushort4(hi[0], hi[1], hi[2], hi[3]);
    *(ushort4*)&Wlo[o] = make_ushort4(lo[0], lo[1], lo[2], lo[3]);
}

// ---------------------------------------------------------------------------
// Kernel 3: fused finalize (vec8) + pheno gather (R8-measured).
// ---------------------------------------------------------------------------
__global__ __launch_bounds__(256) void finalize_fused(
    const float* __restrict__ pt_sum, const float* __restrict__ cnt,
    const float* __restrict__ tsum, const float* __restrict__ tcnt,
    const unsigned* __restrict__ fmax, const float* __restrict__ phenos,
    unsigned short* __restrict__ fphi, unsigned short* __restrict__ fplo,
    float* __restrict__ uni)
{
    if (blockIdx.x < 1024) {
        int e8 = blockIdx.x * 256 + threadIdx.x;     // 8-elem group id
        int e  = e8 * 8;
        int p = e >> 10, col0 = e & 1023;
        int seg = p * T_ + (col0 >> 7);              // all 8 share the task block
        ushort hi[8], lo[8];
        if (p < P_) {
            float c = cnt[seg];
            float4 a = *(const float4*)&pt_sum[e];
            float4 b = *(const float4*)&pt_sum[e + 4];
            float vv[8] = {a.x, a.y, a.z, a.w, b.x, b.y, b.z, b.w};
#pragma unroll
            for (int q = 0; q < 8; ++q) {
                float v;
                if (c > 0.f) v = vv[q] / c;
                else         v = tsum[col0 + q] / fmaxf(tcnt[col0 >> 7], 1.0f);
                unsigned h = f2bf_rne(v);
                hi[q] = (ushort)h;
                lo[q] = (ushort)f2bf_rne(v - bf2f(h));
            }
        } else {
#pragma unroll
            for (int q = 0; q < 8; ++q) { hi[q] = 0; lo[q] = 0; }
        }
        *(ushort4*)&fphi[e]     = make_ushort4(hi[0], hi[1], hi[2], hi[3]);
        *(ushort4*)&fphi[e + 4] = make_ushort4(hi[4], hi[5], hi[6], hi[7]);
        *(ushort4*)&fplo[e]     = make_ushort4(lo[0], lo[1], lo[2], lo[3]);
        *(ushort4*)&fplo[e + 4] = make_ushort4(lo[4], lo[5], lo[6], lo[7]);
    } else {
        int g = (blockIdx.x - 1024) * 256 + threadIdx.x;
        if (g < P_ * NP_) {
            int p = g / NP_, j = g - p * NP_;
            unsigned fm = fmax[p];
            int idx = fm ? (int)(N_SAMP - fm) : N_SAMP - 1;   // no valid -> clip
            uni[g] = phenos[(size_t)idx * NP_ + j];
        }
    }
}

// ---------------------------------------------------------------------------
// Kernel 4: MFMA split GEMM, BARRIER-FREE wave-private pipeline.
// Each wave stages its OWN 16 chunks (4 A-tiles + 4 B-tiles, hi+lo; 1KB each)
// into a private 32KB LDS region, double-buffered (2 K-steps in flight).
// No __syncthreads anywhere: no cross-wave LDS deps -> counted per-wave
// s_waitcnt vmcnt(16) [m135 semantics] replaces the vmcnt(0)+barrier drain
// that left the old kernel 3.5x off its LDS roofline (MfmaUtil 22%).
// lgkmcnt(0) before re-staging a buffer orders ds_read completion vs the
// incoming gload LDS-writes. LDS = 4 waves x 2 bufs x 16KB = 128 KiB.
// ---------------------------------------------------------------------------
template<int OUTF32>
__global__ __launch_bounds__(256, 1) void gemm_split(
    const unsigned short* __restrict__ Ahi, const unsigned short* __restrict__ Alo,
    const unsigned short* __restrict__ Bhi, const unsigned short* __restrict__ Blo,
    const float* __restrict__ bias,
    float* __restrict__ Cf, unsigned short* __restrict__ Chi,
    unsigned short* __restrict__ Clo, int K)
{
    __shared__ __align__(16) char lds[4][2][16384];   // 128 KiB, wave-private
    int tid  = threadIdx.x;
    int lane = tid & 63, w = tid >> 6;
    int wr = w >> 1, wc = w & 1;
    int row0 = blockIdx.y * 128, col0 = blockIdx.x * 128;

    // per-lane fragment source coords (lane l holds X[l&15][k0+(l>>4)*8..+7])
    int fr = lane & 15;
    int fk = (lane >> 4) * 8;

    // chunk c in [0,16): c<8 -> A tile i=(c>>1), piece h=c&1; c>=8 -> B tile.
    const unsigned short* cbase[16];
#pragma unroll
    for (int c = 0; c < 16; ++c) {
        int isB = c >> 3, i = (c >> 1) & 3, h = c & 1;
        const unsigned short* src = isB ? (h ? Blo : Bhi) : (h ? Alo : Ahi);
        int rb = (isB ? col0 + (wc * 4 + i) * 16 : row0 + (wr * 4 + i) * 16) + fr;
        cbase[c] = src + (size_t)rb * K + fk;
    }
    char* wlds = &lds[w][0][0];

    auto STAGE = [&](int buf, int t) {
        int k0 = t * 32;
#pragma unroll
        for (int c = 0; c < 16; ++c)
            gload16(cbase[c] + k0, wlds + buf * 16384 + c * 1024);
    };

    f32x4 acc[4][4] = {};
    int nt = K / 32;
    STAGE(0, 0);
    STAGE(1, 1);
    int lo16 = lane * 16;

    for (int t = 0; t < nt; ++t) {
        int cur = t & 1;
        if (t + 1 < nt) asm volatile("s_waitcnt vmcnt(16)" ::: "memory");
        else            asm volatile("s_waitcnt vmcnt(0)"  ::: "memory");
        const char* b = wlds + cur * 16384;
        bf16x8 ah[4], al[4], bh[4], bl[4];
#pragma unroll
        for (int i = 0; i < 4; ++i) {
            ah[i] = *(const bf16x8*)(b + (i * 2 + 0) * 1024 + lo16);
            al[i] = *(const bf16x8*)(b + (i * 2 + 1) * 1024 + lo16);
        }
#pragma unroll
        for (int j = 0; j < 4; ++j) {
            bh[j] = *(const bf16x8*)(b + (8 + j * 2 + 0) * 1024 + lo16);
            bl[j] = *(const bf16x8*)(b + (8 + j * 2 + 1) * 1024 + lo16);
        }
#pragma unroll
        for (int i = 0; i < 4; ++i)
#pragma unroll
            for (int j = 0; j < 4; ++j) {
                acc[i][j] = __builtin_amdgcn_mfma_f32_16x16x32_bf16(ah[i], bh[j], acc[i][j], 0, 0, 0);
                acc[i][j] = __builtin_amdgcn_mfma_f32_16x16x32_bf16(ah[i], bl[j], acc[i][j], 0, 0, 0);
                acc[i][j] = __builtin_amdgcn_mfma_f32_16x16x32_bf16(al[i], bh[j], acc[i][j], 0, 0, 0);
            }
        if (t + 2 < nt) {
            // ds_reads of buf cur must complete before gloads overwrite it
            asm volatile("s_waitcnt lgkmcnt(0)" ::: "memory");
            STAGE(cur, t + 2);
        }
    }

    // Epilogue: C/D layout col=lane&15, row=(lane>>4)*4+reg  [m89-verified]
#pragma unroll
    for (int i = 0; i < 4; ++i) {
        int r = row0 + wr * 64 + i * 16 + (lane >> 4) * 4;
#pragma unroll
        for (int j = 0; j < 4; ++j) {
            int c = col0 + wc * 64 + j * 16 + (lane & 15);
            float bv = bias[c];
#pragma unroll
            for (int q = 0; q < 4; ++q) {
                float x = fmaxf(acc[i][j][q] + bv, 0.f);
                size_t o = (size_t)(r + q) * H_ + c;
                if (OUTF32) {
                    Cf[o] = x;
                } else {
                    unsigned hb = f2bf_rne(x);
                    Chi[o] = (unsigned short)hb;
                    Clo[o] = (unsigned short)f2bf_rne(x - bf2f(hb));
                }
            }
        }
    }
}

// ---------------------------------------------------------------------------
// Kernel 5: head GEMM + sigmoid, W3 staged in LDS (R8-measured).
// ---------------------------------------------------------------------------
__global__ __launch_bounds__(256) void out_head(
    const float* __restrict__ h2, const float* __restrict__ W3,
    const float* __restrict__ b3, float* __restrict__ out,
    float* __restrict__ latent)
{
    __shared__ float w3s[H_ * NP_];            // 73,728 B
    int tid = threadIdx.x;
    for (int e = tid * 4; e < H_ * NP_; e += 1024)
        *(float4*)&w3s[e] = *(const float4*)&W3[e];
    __syncthreads();

    int wid  = blockIdx.x * 4 + (tid >> 6);
    int lane = tid & 63;
    if (wid >= P_) return;
    const float* hrow = h2 + (size_t)wid * H_;
    float acc[NP_] = {};
    for (int k = lane; k < H_; k += 64) {
        float h = hrow[k];
#pragma unroll
        for (int j = 0; j < NP_; ++j) acc[j] = fmaf(h, w3s[k * NP_ + j], acc[j]);
    }
#pragma unroll
    for (int off = 32; off > 0; off >>= 1)
#pragma unroll
        for (int j = 0; j < NP_; ++j) acc[j] += __shfl_down(acc[j], off);
    if (lane == 0) {
#pragma unroll
        for (int j = 0; j < NP_; ++j) {
            float v = acc[j] + b3[j];
            latent[wid * NP_ + j] = v;
            out[wid * NP_ + j]    = 1.f / (1.f + expf(-v));
        }
    }
}

// ---------------------------------------------------------------------------
extern "C" void kernel_launch(void* const* d_in, const int* in_sizes, int n_in,
                              void* d_out, int out_size, void* d_ws, size_t ws_size,
                              hipStream_t stream)
{
    const float* motion_z = (const float*)d_in[0];
    const int*   tasks    = (const int*)d_in[1];
    const int*   tmask    = (const int*)d_in[2];
    const int*   pids     = (const int*)d_in[3];
    const float* phenos   = (const float*)d_in[4];
    const int*   pmask    = (const int*)d_in[5];
    const float* W1 = (const float*)d_in[6];
    const float* b1 = (const float*)d_in[7];
    const float* W2 = (const float*)d_in[8];
    const float* b2 = (const float*)d_in[9];
    const float* W3 = (const float*)d_in[10];
    const float* b3 = (const float*)d_in[11];

    char* ws = (char*)d_ws;
    float*          pt_sum = (float*)(ws + OFF_PTSUM);
    float*          cnt    = (float*)(ws + OFF_CNT);
    float*          tsum   = (float*)(ws + OFF_TSUM);
    float*          tcnt   = (float*)(ws + OFF_TCNT);
    unsigned*       fmax   = (unsigned*)(ws + OFF_FMAX);
    unsigned short* fphi   = (unsigned short*)(ws + OFF_FPHI);
    unsigned short* fplo   = (unsigned short*)(ws + OFF_FPLO);
    unsigned short* w1thi  = (unsigned short*)(ws + OFF_W1THI);
    unsigned short* w1tlo  = (unsigned short*)(ws + OFF_W1TLO);
    unsigned short* h1hi   = (unsigned short*)(ws + OFF_H1HI);
    unsigned short* h1lo   = (unsigned short*)(ws + OFF_H1LO);
    unsigned short* w2thi  = (unsigned short*)(ws + OFF_W2THI);
    unsigned short* w2tlo  = (unsigned short*)(ws + OFF_W2TLO);
    float*          h2     = (float*)(ws + OFF_H2);

    float* out    = (float*)d_out;
    float* uni    = out + P_ * NP_;
    float* latent = out + 2 * P_ * NP_;

    // Node 1: single memset covers pt_sum | cnt | tsum | tcnt | fmax
    hipMemsetAsync(ws, 0, ZERO_BYTES, stream);

    // Node 2: block-compaction scatter
    scatter_pt<<<782, 256, 0, stream>>>(motion_z, tasks, tmask, pids, pmask,
                                        pt_sum, cnt, fmax);
    // Node 3: task-sum partials + both weight transposes (fused)
    mid_fused<<<125 + 6144, 256, 0, stream>>>(pt_sum, cnt, tsum, tcnt,
                                              W1, W2, w1thi, w1tlo, w2thi, w2tlo);
    // Node 4: finalize fingerprint (vec8) + pheno gather
    finalize_fused<<<1024 + (P_ * NP_ + 255) / 256, 256, 0, stream>>>(
        pt_sum, cnt, tsum, tcnt, fmax, phenos, fphi, fplo, uni);

    // Node 5: GEMM1 fingerprint[2048,1024] @ W1 -> h1 (relu, bf16 hi/lo out)
    gemm_split<0><<<dim3(16, 16), 256, 0, stream>>>(
        fphi, fplo, w1thi, w1tlo, b1, nullptr, h1hi, h1lo, 1024);
    // Node 6: GEMM2 h1[2048,2048] @ W2 -> h2 (relu, f32 out)
    gemm_split<1><<<dim3(16, 16), 256, 0, stream>>>(
        h1hi, h1lo, w2thi, w2tlo, b2, h2, nullptr, nullptr, H_);

    // Node 7: head + sigmoid
    out_head<<<P_ / 4, 256, 0, stream>>>(h2, W3, b3, out, latent);
}